// Round 13
// baseline (202.248 us; speedup 1.0000x reference)
//
#include <hip/hip_runtime.h>

typedef __bf16 bf16x8 __attribute__((ext_vector_type(8)));
typedef float f32x4 __attribute__((ext_vector_type(4)));
typedef unsigned short u16;
typedef unsigned int u32;

// native HW bf16 convert (gfx950, RNE)
__device__ __forceinline__ u16 f2bf(float f) {
  return __builtin_bit_cast(u16, (__bf16)f);
}

// async global->LDS, 16B/lane. One call = 64 lanes x 16B = 1024B.
// LDS dest = wave-uniform base + lane*16 (HW rule).
__device__ __forceinline__ void gload16(const u16* g, u16* lds_base) {
  __builtin_amdgcn_global_load_lds(
      (const __attribute__((address_space(1))) void*)g,
      (__attribute__((address_space(3))) void*)lds_base, 16, 0, 0);
}

// ---------------- fused cast fp32 -> bf16 for x, w_qkv, w_proj --------------
__global__ void cast_all(const float* __restrict__ x,  u16* __restrict__ xo,
                         const float* __restrict__ wq, u16* __restrict__ wqo,
                         const float* __restrict__ wp, u16* __restrict__ wpo) {
  const int NX = (2 * 2048 * 1024) / 4;   // float4 units
  const int NQ = (3072 * 1024) / 4;
  const int NP = (1024 * 1024) / 4;
  int i = blockIdx.x * blockDim.x + threadIdx.x;
  int stride = gridDim.x * blockDim.x;
  for (; i < NX + NQ + NP; i += stride) {
    const float4* s; uint2* d; int j;
    if (i < NX)            { s = (const float4*)x;  d = (uint2*)xo;  j = i; }
    else if (i < NX + NQ)  { s = (const float4*)wq; d = (uint2*)wqo; j = i - NX; }
    else                   { s = (const float4*)wp; d = (uint2*)wpo; j = i - NX - NQ; }
    float4 f = s[j];
    uint2 o;
    o.x = (u32)f2bf(f.x) | ((u32)f2bf(f.y) << 16);
    o.y = (u32)f2bf(f.z) | ((u32)f2bf(f.w) << 16);
    d[j] = o;
  }
}

// ---------------- bf16 MFMA GEMM: C[M,N] = A[M,K] * W[N,K]^T + bias ----------
// CHAMPION structure: BM x BN block tile, 4 waves (2x2), BK=32,
// double-buffered LDS, one barrier per K-iter, XCD-aware swizzle.
template<int OUT_BF16, int BM, int BN>
__global__ __launch_bounds__(256) void gemm_nt(
    const u16* __restrict__ A, const u16* __restrict__ W,
    const float* __restrict__ bias, void* __restrict__ Cout,
    int M, int N, int K)
{
  constexpr int MT = BM / 32;             // m-tiles per wave
  constexpr int NT = BN / 32;             // n-tiles per wave
  __shared__ u16 Alds[2][BM][32];
  __shared__ u16 Blds[2][BN][32];
  const int tid  = threadIdx.x;
  const int lane = tid & 63;
  const int wave = tid >> 6;
  const int wm = (wave >> 1) * (BM / 2);
  const int wn = (wave & 1) * (BN / 2);

  const int b    = blockIdx.x;
  const int xcd  = b & 7;
  const int slot = b >> 3;
  const int npx  = (N / BN) >> 3;         // n-columns owned per XCD
  const int m0 = (slot / npx) * BM;
  const int n0 = (xcd * npx + slot % npx) * BN;

  const int quad = lane >> 4;
  const int li   = lane & 15;

  const u16* ga = &A[(size_t)(m0 + wave * (BM / 4) + (lane >> 2)) * K + (lane & 3) * 8];
  const u16* gb = &W[(size_t)(n0 + wave * (BN / 4) + (lane >> 2)) * K + (lane & 3) * 8];

  auto stage = [&](int buf, int k0) {
#pragma unroll
    for (int i = 0; i < BM / 64; i++)
      gload16(ga + (size_t)i * 16 * K + k0, &Alds[buf][wave * (BM / 4) + i * 16][0]);
#pragma unroll
    for (int i = 0; i < BN / 64; i++)
      gload16(gb + (size_t)i * 16 * K + k0, &Blds[buf][wave * (BN / 4) + i * 16][0]);
  };

  f32x4 acc[MT][NT] = {};
  const int niter = K / 32;

  stage(0, 0);                            // prologue: tile 0 -> buf 0

#pragma unroll 2
  for (int kt = 0; kt < niter; kt++) {
    __syncthreads();                      // drains tile kt (one compute phase old)
    if (kt + 1 < niter) stage((kt + 1) & 1, (kt + 1) * 32);
    const int buf = kt & 1;
    bf16x8 af[MT], bfr[NT];
#pragma unroll
    for (int t = 0; t < MT; t++)
      af[t] = *(const bf16x8*)&Alds[buf][wm + t * 16 + li][quad * 8];
#pragma unroll
    for (int t = 0; t < NT; t++)
      bfr[t] = *(const bf16x8*)&Blds[buf][wn + t * 16 + li][quad * 8];
#pragma unroll
    for (int mt = 0; mt < MT; mt++)
#pragma unroll
      for (int nt = 0; nt < NT; nt++)
        acc[mt][nt] = __builtin_amdgcn_mfma_f32_16x16x32_bf16(af[mt], bfr[nt], acc[mt][nt], 0, 0, 0);
  }

#pragma unroll
  for (int mt = 0; mt < MT; mt++)
#pragma unroll
    for (int nt = 0; nt < NT; nt++) {
      int gn = n0 + wn + nt * 16 + li;
      float bv = bias[gn];
#pragma unroll
      for (int r = 0; r < 4; r++) {
        int gm = m0 + wm + mt * 16 + quad * 4 + r;
        float v = acc[mt][nt][r] + bv;
        if (OUT_BF16)
          ((u16*)Cout)[(size_t)gm * N + gn] = f2bf(v);
        else
          ((float*)Cout)[(size_t)gm * N + gn] = v;
      }
    }
}

// ---------------- GEMM2: 128x128, BK=64, swizzled LDS, fp32 out -------------
__global__ __launch_bounds__(256) void gemm_nt64(
    const u16* __restrict__ A, const u16* __restrict__ W,
    const float* __restrict__ bias, float* __restrict__ Cout,
    int M, int N, int K)
{
  __shared__ u16 Alds[2][128][64];
  __shared__ u16 Blds[2][128][64];
  const int tid  = threadIdx.x;
  const int lane = tid & 63;
  const int wave = tid >> 6;
  const int wm = (wave >> 1) * 64;
  const int wn = (wave & 1) * 64;

  const int b    = blockIdx.x;
  const int xcd  = b & 7;
  const int slot = b >> 3;
  const int npx  = (N / 128) >> 3;        // 1 for N=1024
  const int m0 = (slot / npx) * 128;
  const int n0 = (xcd * npx + slot % npx) * 128;

  const int quad = lane >> 4;
  const int li   = lane & 15;

  // staging: lane l covers row 8-group r8 = l>>3, fetches data-block (l&7)^r8
  const int r8 = lane >> 3;
  const int db = (lane & 7) ^ r8;
  const u16* ga = A + (size_t)(m0 + wave * 32 + r8) * K + db * 8;
  const u16* gb = W + (size_t)(n0 + wave * 32 + r8) * K + db * 8;

  auto stage = [&](int buf, int k0) {
#pragma unroll
    for (int i = 0; i < 4; i++)
      gload16(ga + (size_t)(i * 8) * K + k0, &Alds[buf][wave * 32 + i * 8][0]);
#pragma unroll
    for (int i = 0; i < 4; i++)
      gload16(gb + (size_t)(i * 8) * K + k0, &Blds[buf][wave * 32 + i * 8][0]);
  };

  f32x4 acc[4][4] = {};
  const int niter = K / 64;               // 16

  stage(0, 0);                            // prologue

  for (int kt = 0; kt < niter; kt++) {
    __syncthreads();                      // drains stage(kt)
    if (kt + 1 < niter) stage((kt + 1) & 1, (kt + 1) * 64);
    const int buf = kt & 1;
    bf16x8 af[4][2], bfr[4][2];
#pragma unroll
    for (int t = 0; t < 4; t++)
#pragma unroll
      for (int k = 0; k < 2; k++) {
        const int pos = ((k * 4 + quad) ^ (li & 7)) * 8;
        af[t][k]  = *(const bf16x8*)&Alds[buf][wm + t * 16 + li][pos];
        bfr[t][k] = *(const bf16x8*)&Blds[buf][wn + t * 16 + li][pos];
      }
#pragma unroll
    for (int mt = 0; mt < 4; mt++)
#pragma unroll
      for (int nt = 0; nt < 4; nt++)
#pragma unroll
        for (int k = 0; k < 2; k++)
          acc[mt][nt] = __builtin_amdgcn_mfma_f32_16x16x32_bf16(
              af[mt][k], bfr[nt][k], acc[mt][nt], 0, 0, 0);
  }

#pragma unroll
  for (int mt = 0; mt < 4; mt++)
#pragma unroll
    for (int nt = 0; nt < 4; nt++) {
      int gn = n0 + wn + nt * 16 + li;
      float bv = bias[gn];
#pragma unroll
      for (int r = 0; r < 4; r++) {
        int gm = m0 + wm + mt * 16 + quad * 4 + r;
        Cout[(size_t)gm * N + gn] = acc[mt][nt][r] + bv;
      }
    }
}

// ---------------- sliding-window flash attention -----------------------------
// CHAMPION (157.06): R0 staging structure + R5 XCD swizzle + R9 VALU trims.
// R12's 2-deep prefetch regressed +18us (register cliff under lb(256,4) ->
// scratch spills) -> reverted to single prefetch.
__global__ __launch_bounds__(256, 4) void attn_kernel(const u16* __restrict__ qkv,
                                                      u16* __restrict__ aout)
{
  const int L = 2048, DQ = 3072, D = 1024;
  // chunked XCD transform on flat grid of 1024 (1024 % 8 == 0 -> bijective)
  const int bid  = blockIdx.x;
  const int wgid = (bid & 7) * 128 + (bid >> 3);
  const int qt = wgid & 31;
  const int h  = (wgid >> 5) & 15;
  const int b  = wgid >> 9;
  const int q0 = qt * 64;
  const int tid  = threadIdx.x;
  const int lane = tid & 63;
  const int wave = tid >> 6;
  const int quad = lane >> 4;
  const int li   = lane & 15;

  __shared__ u16 Klds[64][68];      // [key][e], +4 pad
  __shared__ u16 Vt[64][68];        // [e][key], +4 pad
  __shared__ u16 Plds[4][16][68];   // per-wave P transpose buffer

  const u16* base = qkv + (size_t)b * L * DQ + h * 64;

  bf16x8 qf[2];
  {
    const u16* qsrc = base + (size_t)(q0 + wave * 16 + li) * DQ;
    qf[0] = *(const bf16x8*)&qsrc[quad * 8];
    qf[1] = *(const bf16x8*)&qsrc[32 + quad * 8];
  }

  f32x4 O[4] = {};
  float lsum[4] = {0.f, 0.f, 0.f, 0.f};

  const float C1 = 0.18033688011112042f;  // 0.125 * log2(e)
  const float C2 = 17.312340490667562f;   // 12 * log2(e)
  const int gq = q0 + wave * 16 + quad * 4;  // + r

  const int sr2 = (tid >> 3) * 2, sc = (tid & 7) * 8;
  const u16* ksbase = base + D;
  const u16* vsbase = base + 2 * D;
  uint4 kr0, kr1, vr0, vr1;
  auto loadkv = [&](int t) {
    int kb = q0 - 256 + t * 64;
    const u16* ks = ksbase + (size_t)kb * DQ;
    const u16* vs = vsbase + (size_t)kb * DQ;
    kr0 = *(const uint4*)&ks[(size_t)sr2 * DQ + sc];
    kr1 = *(const uint4*)&ks[(size_t)(sr2 + 1) * DQ + sc];
    vr0 = *(const uint4*)&vs[(size_t)sr2 * DQ + sc];
    vr1 = *(const uint4*)&vs[(size_t)(sr2 + 1) * DQ + sc];
  };

  const int t0 = (qt < 4) ? (4 - qt) : 0;   // first valid K-block
  loadkv(t0);

  for (int t = t0; t < 5; t++) {
    const int kb = q0 - 256 + t * 64;
    __syncthreads();
    *(uint4*)&Klds[sr2][sc]     = kr0;
    *(uint4*)&Klds[sr2 + 1][sc] = kr1;
    {
      u32 a0[4] = {vr0.x, vr0.y, vr0.z, vr0.w};
      u32 a1[4] = {vr1.x, vr1.y, vr1.z, vr1.w};
#pragma unroll
      for (int j2 = 0; j2 < 4; j2++) {
        u32 lo0 = a0[j2] & 0xffffu, hi0 = a0[j2] >> 16;
        u32 lo1 = a1[j2] & 0xffffu, hi1 = a1[j2] >> 16;
        *(u32*)&Vt[sc + 2 * j2][sr2]     = lo0 | (lo1 << 16);
        *(u32*)&Vt[sc + 2 * j2 + 1][sr2] = hi0 | (hi1 << 16);
      }
    }
    __syncthreads();
    if (t + 1 < 5) loadkv(t + 1);

    f32x4 sacc[4] = {};
#pragma unroll
    for (int nt = 0; nt < 4; nt++) {
      bf16x8 kf0 = *(const bf16x8*)&Klds[nt * 16 + li][quad * 8];
      bf16x8 kf1 = *(const bf16x8*)&Klds[nt * 16 + li][32 + quad * 8];
      sacc[nt] = __builtin_amdgcn_mfma_f32_16x16x32_bf16(qf[0], kf0, sacc[nt], 0, 0, 0);
      sacc[nt] = __builtin_amdgcn_mfma_f32_16x16x32_bf16(qf[1], kf1, sacc[nt], 0, 0, 0);
    }

    const bool needmask = (t == 0) || (t == 4);
#pragma unroll
    for (int nt = 0; nt < 4; nt++) {
      int gj = kb + nt * 16 + li;
#pragma unroll
      for (int r = 0; r < 4; r++) {
        float e = __builtin_amdgcn_exp2f(__builtin_fmaf(sacc[nt][r], C1, -C2));
        float p;
        if (needmask) {
          bool masked = (gj > gq + r) || ((gq + r) - gj >= 256);
          p = masked ? 0.f : e;
        } else {
          p = e;
        }
        lsum[r] += p;
        Plds[wave][quad * 4 + r][nt * 16 + li] = f2bf(p);
      }
    }

    bf16x8 pf0 = *(const bf16x8*)&Plds[wave][li][quad * 8];
    bf16x8 pf1 = *(const bf16x8*)&Plds[wave][li][32 + quad * 8];
#pragma unroll
    for (int nt = 0; nt < 4; nt++) {
      bf16x8 vb0 = *(const bf16x8*)&Vt[nt * 16 + li][quad * 8];
      bf16x8 vb1 = *(const bf16x8*)&Vt[nt * 16 + li][32 + quad * 8];
      O[nt] = __builtin_amdgcn_mfma_f32_16x16x32_bf16(pf0, vb0, O[nt], 0, 0, 0);
      O[nt] = __builtin_amdgcn_mfma_f32_16x16x32_bf16(pf1, vb1, O[nt], 0, 0, 0);
    }
  }

#pragma unroll
  for (int d = 1; d < 16; d <<= 1)
#pragma unroll
    for (int r = 0; r < 4; r++)
      lsum[r] += __shfl_xor(lsum[r], d, 64);
#pragma unroll
  for (int r = 0; r < 4; r++) {
    float inv = 1.f / lsum[r];
#pragma unroll
    for (int nt = 0; nt < 4; nt++)
      aout[(size_t)(b * L + gq + r) * D + h * 64 + nt * 16 + li] = f2bf(O[nt][r] * inv);
  }
}

// ---------------- launcher ---------------------------------------------------
// R13: champion config + gemm_nt64 TRIPLE-LAUNCH diagnostic (idempotent —
// pure function of attn_bf/wproj_bf -> out). dur = champion + 2*T_gemm2.
// Pre-committed: T_gemm2 >= 12us -> one occupancy round on gemm2;
// <= 8us -> resubmit champion as final, declare practical ceiling.
extern "C" void kernel_launch(void* const* d_in, const int* in_sizes, int n_in,
                              void* d_out, int out_size, void* d_ws, size_t ws_size,
                              hipStream_t stream) {
  const float* x      = (const float*)d_in[0];
  const float* w_qkv  = (const float*)d_in[1];
  const float* b_qkv  = (const float*)d_in[2];
  const float* w_proj = (const float*)d_in[3];
  const float* b_proj = (const float*)d_in[4];
  float* out = (float*)d_out;

  char* ws = (char*)d_ws;
  u16* x_bf     = (u16*)(ws);                         //  8 MB: [4096,1024] bf16
  u16* wqkv_bf  = (u16*)(ws + ((size_t)8  << 20));    //  6 MB: [3072,1024] bf16
  u16* wproj_bf = (u16*)(ws + ((size_t)14 << 20));    //  2 MB: [1024,1024] bf16
  u16* qkv_bf   = (u16*)(ws + ((size_t)16 << 20));    // 24 MB: [4096,3072] bf16
  u16* attn_bf  = (u16*)(ws + ((size_t)40 << 20));    //  8 MB: [4096,1024] bf16

  cast_all<<<2048, 256, 0, stream>>>(x, x_bf, w_qkv, wqkv_bf, w_proj, wproj_bf);

  // GEMM1: 44.0 us champion (128x128, 768 blocks, 3/CU)
  gemm_nt<1, 128, 128><<<(4096 / 128) * (3072 / 128), 256, 0, stream>>>(
      x_bf, wqkv_bf, b_qkv, qkv_bf, 4096, 3072, 1024);

  // attn: champion (single prefetch, VALU trims, XCD swizzle)
  attn_kernel<<<1024, 256, 0, stream>>>(qkv_bf, attn_bf);

  // GEMM2 diagnostic triple-launch (identical, idempotent)
  gemm_nt64<<<(4096 / 128) * (1024 / 128), 256, 0, stream>>>(
      attn_bf, wproj_bf, b_proj, out, 4096, 1024, 1024);
  gemm_nt64<<<(4096 / 128) * (1024 / 128), 256, 0, stream>>>(
      attn_bf, wproj_bf, b_proj, out, 4096, 1024, 1024);
  gemm_nt64<<<(4096 / 128) * (1024 / 128), 256, 0, stream>>>(
      attn_bf, wproj_bf, b_proj, out, 4096, 1024, 1024);
}

// Round 15
// 154.791 us; speedup vs baseline: 1.3066x; 1.3066x over previous
//
#include <hip/hip_runtime.h>

typedef __bf16 bf16x8 __attribute__((ext_vector_type(8)));
typedef float f32x4 __attribute__((ext_vector_type(4)));
typedef unsigned short u16;
typedef unsigned int u32;

// native HW bf16 convert (gfx950, RNE)
__device__ __forceinline__ u16 f2bf(float f) {
  return __builtin_bit_cast(u16, (__bf16)f);
}

// async global->LDS, 16B/lane. One call = 64 lanes x 16B = 1024B.
// LDS dest = wave-uniform base + lane*16 (HW rule).
__device__ __forceinline__ void gload16(const u16* g, u16* lds_base) {
  __builtin_amdgcn_global_load_lds(
      (const __attribute__((address_space(1))) void*)g,
      (__attribute__((address_space(3))) void*)lds_base, 16, 0, 0);
}

// ---------------- fused cast fp32 -> bf16 for x, w_qkv, w_proj --------------
__global__ void cast_all(const float* __restrict__ x,  u16* __restrict__ xo,
                         const float* __restrict__ wq, u16* __restrict__ wqo,
                         const float* __restrict__ wp, u16* __restrict__ wpo) {
  const int NX = (2 * 2048 * 1024) / 4;   // float4 units
  const int NQ = (3072 * 1024) / 4;
  const int NP = (1024 * 1024) / 4;
  int i = blockIdx.x * blockDim.x + threadIdx.x;
  int stride = gridDim.x * blockDim.x;
  for (; i < NX + NQ + NP; i += stride) {
    const float4* s; uint2* d; int j;
    if (i < NX)            { s = (const float4*)x;  d = (uint2*)xo;  j = i; }
    else if (i < NX + NQ)  { s = (const float4*)wq; d = (uint2*)wqo; j = i - NX; }
    else                   { s = (const float4*)wp; d = (uint2*)wpo; j = i - NX - NQ; }
    float4 f = s[j];
    uint2 o;
    o.x = (u32)f2bf(f.x) | ((u32)f2bf(f.y) << 16);
    o.y = (u32)f2bf(f.z) | ((u32)f2bf(f.w) << 16);
    d[j] = o;
  }
}

// ---------------- GEMM1: 128x128 BK=32, 4 waves, 2-barrier dbuf -------------
// CHAMPION structure + LDS anti-conflict swizzle. R13 PMC: 3.1M
// SQ_LDS_BANK_CONFLICT — old frag read (16 lanes of an LDS phase share quad
// -> same 16B column of 64B rows) was an 8-way conflict.
// Fix (rule 21 both-sides): 16B data-block b of row r stored at position
// b ^ ((r>>1)&3); gload SOURCE pre-swizzled (lane l fetches block
// (l&3)^((l>>3)&3)), dest linear; frag read position quad ^ ((li>>1)&3)
// -> 2 lanes per 4-bank group = free (m136).
template<int OUT_BF16, int BM, int BN>
__global__ __launch_bounds__(256) void gemm_nt(
    const u16* __restrict__ A, const u16* __restrict__ W,
    const float* __restrict__ bias, void* __restrict__ Cout,
    int M, int N, int K)
{
  constexpr int MT = BM / 32;             // m-tiles per wave
  constexpr int NT = BN / 32;             // n-tiles per wave
  __shared__ u16 Alds[2][BM][32];
  __shared__ u16 Blds[2][BN][32];
  const int tid  = threadIdx.x;
  const int lane = tid & 63;
  const int wave = tid >> 6;
  const int wm = (wave >> 1) * (BM / 2);
  const int wn = (wave & 1) * (BN / 2);

  const int b    = blockIdx.x;
  const int xcd  = b & 7;
  const int slot = b >> 3;
  const int npx  = (N / BN) >> 3;         // n-columns owned per XCD
  const int m0 = (slot / npx) * BM;
  const int n0 = (xcd * npx + slot % npx) * BN;

  const int quad = lane >> 4;
  const int li   = lane & 15;

  // pre-swizzled staging source: lane l covers row l>>2, fetches data block
  // (l&3) ^ ((l>>3)&3) so that linear dest pos (l&3) holds b ^ ((r>>1)&3)
  const int scol = ((lane & 3) ^ ((lane >> 3) & 3)) * 8;
  const u16* ga = &A[(size_t)(m0 + wave * (BM / 4) + (lane >> 2)) * K + scol];
  const u16* gb = &W[(size_t)(n0 + wave * (BN / 4) + (lane >> 2)) * K + scol];

  auto stage = [&](int buf, int k0) {
#pragma unroll
    for (int i = 0; i < BM / 64; i++)
      gload16(ga + (size_t)i * 16 * K + k0, &Alds[buf][wave * (BM / 4) + i * 16][0]);
#pragma unroll
    for (int i = 0; i < BN / 64; i++)
      gload16(gb + (size_t)i * 16 * K + k0, &Blds[buf][wave * (BN / 4) + i * 16][0]);
  };

  f32x4 acc[MT][NT] = {};
  const int niter = K / 32;

  stage(0, 0);                            // prologue: tile 0 -> buf 0

  const int rpos = (quad ^ ((li >> 1) & 3)) * 8;   // swizzled read position

#pragma unroll 2
  for (int kt = 0; kt < niter; kt++) {
    __syncthreads();                      // drains tile kt (one compute phase old)
    if (kt + 1 < niter) stage((kt + 1) & 1, (kt + 1) * 32);
    const int buf = kt & 1;
    bf16x8 af[MT], bfr[NT];
#pragma unroll
    for (int t = 0; t < MT; t++)
      af[t] = *(const bf16x8*)&Alds[buf][wm + t * 16 + li][rpos];
#pragma unroll
    for (int t = 0; t < NT; t++)
      bfr[t] = *(const bf16x8*)&Blds[buf][wn + t * 16 + li][rpos];
#pragma unroll
    for (int mt = 0; mt < MT; mt++)
#pragma unroll
      for (int nt = 0; nt < NT; nt++)
        acc[mt][nt] = __builtin_amdgcn_mfma_f32_16x16x32_bf16(af[mt], bfr[nt], acc[mt][nt], 0, 0, 0);
  }

#pragma unroll
  for (int mt = 0; mt < MT; mt++)
#pragma unroll
    for (int nt = 0; nt < NT; nt++) {
      int gn = n0 + wn + nt * 16 + li;
      float bv = bias[gn];
#pragma unroll
      for (int r = 0; r < 4; r++) {
        int gm = m0 + wm + mt * 16 + quad * 4 + r;
        float v = acc[mt][nt][r] + bv;
        if (OUT_BF16)
          ((u16*)Cout)[(size_t)gm * N + gn] = f2bf(v);
        else
          ((float*)Cout)[(size_t)gm * N + gn] = v;
      }
    }
}

// ---------------- GEMM2: 128x128, BK=64, 8 waves (512 thr), fp32 out --------
// R13 diagnostic: T_gemm2 = 22.6us (~380 TF) at 256 thr = 1 wave/SIMD ->
// zero latency hiding. 512 thr = 8 waves (2m x 4n, wave tile 64x32) =
// 2 waves/SIMD (gemm256's occupancy, 570 TF). Same tile, same bytes, same
// swizzled-LDS layout (pos = (k*4+quad)^(li&7), 2-way free).
__global__ __launch_bounds__(512) void gemm_nt64(
    const u16* __restrict__ A, const u16* __restrict__ W,
    const float* __restrict__ bias, float* __restrict__ Cout,
    int M, int N, int K)
{
  __shared__ u16 Alds[2][128][64];
  __shared__ u16 Blds[2][128][64];
  const int tid  = threadIdx.x;
  const int lane = tid & 63;
  const int wave = tid >> 6;              // 0..7
  const int wm = (wave >> 2) * 64;        // 2 wave-rows
  const int wn = (wave & 3) * 32;         // 4 wave-cols

  const int b    = blockIdx.x;
  const int xcd  = b & 7;
  const int slot = b >> 3;
  const int npx  = (N / 128) >> 3;        // 1 for N=1024
  const int m0 = (slot / npx) * 128;
  const int n0 = (xcd * npx + slot % npx) * 128;

  const int quad = lane >> 4;
  const int li   = lane & 15;

  // staging: lane l covers row 8-group r8 = l>>3, fetches data-block (l&7)^r8
  const int r8 = lane >> 3;
  const int db = (lane & 7) ^ r8;
  const u16* ga = A + (size_t)(m0 + wave * 16 + r8) * K + db * 8;
  const u16* gb = W + (size_t)(n0 + wave * 16 + r8) * K + db * 8;

  auto stage = [&](int buf, int k0) {
#pragma unroll
    for (int i = 0; i < 2; i++)
      gload16(ga + (size_t)(i * 8) * K + k0, &Alds[buf][wave * 16 + i * 8][0]);
#pragma unroll
    for (int i = 0; i < 2; i++)
      gload16(gb + (size_t)(i * 8) * K + k0, &Blds[buf][wave * 16 + i * 8][0]);
  };

  f32x4 acc[4][2] = {};
  const int niter = K / 64;               // 16

  stage(0, 0);                            // prologue

  for (int kt = 0; kt < niter; kt++) {
    __syncthreads();                      // drains stage(kt)
    if (kt + 1 < niter) stage((kt + 1) & 1, (kt + 1) * 64);
    const int buf = kt & 1;
    bf16x8 af[4][2], bfr[2][2];
#pragma unroll
    for (int t = 0; t < 4; t++)
#pragma unroll
      for (int k = 0; k < 2; k++) {
        const int pos = ((k * 4 + quad) ^ (li & 7)) * 8;
        af[t][k] = *(const bf16x8*)&Alds[buf][wm + t * 16 + li][pos];
      }
#pragma unroll
    for (int t = 0; t < 2; t++)
#pragma unroll
      for (int k = 0; k < 2; k++) {
        const int pos = ((k * 4 + quad) ^ (li & 7)) * 8;
        bfr[t][k] = *(const bf16x8*)&Blds[buf][wn + t * 16 + li][pos];
      }
#pragma unroll
    for (int mt = 0; mt < 4; mt++)
#pragma unroll
      for (int nt = 0; nt < 2; nt++)
#pragma unroll
        for (int k = 0; k < 2; k++)
          acc[mt][nt] = __builtin_amdgcn_mfma_f32_16x16x32_bf16(
              af[mt][k], bfr[nt][k], acc[mt][nt], 0, 0, 0);
  }

#pragma unroll
  for (int mt = 0; mt < 4; mt++)
#pragma unroll
    for (int nt = 0; nt < 2; nt++) {
      int gn = n0 + wn + nt * 16 + li;
      float bv = bias[gn];
#pragma unroll
      for (int r = 0; r < 4; r++) {
        int gm = m0 + wm + mt * 16 + quad * 4 + r;
        Cout[(size_t)gm * N + gn] = acc[mt][nt][r] + bv;
      }
    }
}

// ---------------- sliding-window flash attention -----------------------------
// CHAMPION (157.06): R0 staging structure + R5 XCD swizzle + R9 VALU trims.
// Measured T_attn = 17.1us (R11). Frozen.
__global__ __launch_bounds__(256, 4) void attn_kernel(const u16* __restrict__ qkv,
                                                      u16* __restrict__ aout)
{
  const int L = 2048, DQ = 3072, D = 1024;
  // chunked XCD transform on flat grid of 1024 (1024 % 8 == 0 -> bijective)
  const int bid  = blockIdx.x;
  const int wgid = (bid & 7) * 128 + (bid >> 3);
  const int qt = wgid & 31;
  const int h  = (wgid >> 5) & 15;
  const int b  = wgid >> 9;
  const int q0 = qt * 64;
  const int tid  = threadIdx.x;
  const int lane = tid & 63;
  const int wave = tid >> 6;
  const int quad = lane >> 4;
  const int li   = lane & 15;

  __shared__ u16 Klds[64][68];      // [key][e], +4 pad
  __shared__ u16 Vt[64][68];        // [e][key], +4 pad
  __shared__ u16 Plds[4][16][68];   // per-wave P transpose buffer

  const u16* base = qkv + (size_t)b * L * DQ + h * 64;

  bf16x8 qf[2];
  {
    const u16* qsrc = base + (size_t)(q0 + wave * 16 + li) * DQ;
    qf[0] = *(const bf16x8*)&qsrc[quad * 8];
    qf[1] = *(const bf16x8*)&qsrc[32 + quad * 8];
  }

  f32x4 O[4] = {};
  float lsum[4] = {0.f, 0.f, 0.f, 0.f};

  const float C1 = 0.18033688011112042f;  // 0.125 * log2(e)
  const float C2 = 17.312340490667562f;   // 12 * log2(e)
  const int gq = q0 + wave * 16 + quad * 4;  // + r

  const int sr2 = (tid >> 3) * 2, sc = (tid & 7) * 8;
  const u16* ksbase = base + D;
  const u16* vsbase = base + 2 * D;
  uint4 kr0, kr1, vr0, vr1;
  auto loadkv = [&](int t) {
    int kb = q0 - 256 + t * 64;
    const u16* ks = ksbase + (size_t)kb * DQ;
    const u16* vs = vsbase + (size_t)kb * DQ;
    kr0 = *(const uint4*)&ks[(size_t)sr2 * DQ + sc];
    kr1 = *(const uint4*)&ks[(size_t)(sr2 + 1) * DQ + sc];
    vr0 = *(const uint4*)&vs[(size_t)sr2 * DQ + sc];
    vr1 = *(const uint4*)&vs[(size_t)(sr2 + 1) * DQ + sc];
  };

  const int t0 = (qt < 4) ? (4 - qt) : 0;   // first valid K-block
  loadkv(t0);

  for (int t = t0; t < 5; t++) {
    const int kb = q0 - 256 + t * 64;
    __syncthreads();
    *(uint4*)&Klds[sr2][sc]     = kr0;
    *(uint4*)&Klds[sr2 + 1][sc] = kr1;
    {
      u32 a0[4] = {vr0.x, vr0.y, vr0.z, vr0.w};
      u32 a1[4] = {vr1.x, vr1.y, vr1.z, vr1.w};
#pragma unroll
      for (int j2 = 0; j2 < 4; j2++) {
        u32 lo0 = a0[j2] & 0xffffu, hi0 = a0[j2] >> 16;
        u32 lo1 = a1[j2] & 0xffffu, hi1 = a1[j2] >> 16;
        *(u32*)&Vt[sc + 2 * j2][sr2]     = lo0 | (lo1 << 16);
        *(u32*)&Vt[sc + 2 * j2 + 1][sr2] = hi0 | (hi1 << 16);
      }
    }
    __syncthreads();
    if (t + 1 < 5) loadkv(t + 1);

    f32x4 sacc[4] = {};
#pragma unroll
    for (int nt = 0; nt < 4; nt++) {
      bf16x8 kf0 = *(const bf16x8*)&Klds[nt * 16 + li][quad * 8];
      bf16x8 kf1 = *(const bf16x8*)&Klds[nt * 16 + li][32 + quad * 8];
      sacc[nt] = __builtin_amdgcn_mfma_f32_16x16x32_bf16(qf[0], kf0, sacc[nt], 0, 0, 0);
      sacc[nt] = __builtin_amdgcn_mfma_f32_16x16x32_bf16(qf[1], kf1, sacc[nt], 0, 0, 0);
    }

    const bool needmask = (t == 0) || (t == 4);
#pragma unroll
    for (int nt = 0; nt < 4; nt++) {
      int gj = kb + nt * 16 + li;
#pragma unroll
      for (int r = 0; r < 4; r++) {
        float e = __builtin_amdgcn_exp2f(__builtin_fmaf(sacc[nt][r], C1, -C2));
        float p;
        if (needmask) {
          bool masked = (gj > gq + r) || ((gq + r) - gj >= 256);
          p = masked ? 0.f : e;
        } else {
          p = e;
        }
        lsum[r] += p;
        Plds[wave][quad * 4 + r][nt * 16 + li] = f2bf(p);
      }
    }

    bf16x8 pf0 = *(const bf16x8*)&Plds[wave][li][quad * 8];
    bf16x8 pf1 = *(const bf16x8*)&Plds[wave][li][32 + quad * 8];
#pragma unroll
    for (int nt = 0; nt < 4; nt++) {
      bf16x8 vb0 = *(const bf16x8*)&Vt[nt * 16 + li][quad * 8];
      bf16x8 vb1 = *(const bf16x8*)&Vt[nt * 16 + li][32 + quad * 8];
      O[nt] = __builtin_amdgcn_mfma_f32_16x16x32_bf16(pf0, vb0, O[nt], 0, 0, 0);
      O[nt] = __builtin_amdgcn_mfma_f32_16x16x32_bf16(pf1, vb1, O[nt], 0, 0, 0);
    }
  }

#pragma unroll
  for (int d = 1; d < 16; d <<= 1)
#pragma unroll
    for (int r = 0; r < 4; r++)
      lsum[r] += __shfl_xor(lsum[r], d, 64);
#pragma unroll
  for (int r = 0; r < 4; r++) {
    float inv = 1.f / lsum[r];
#pragma unroll
    for (int nt = 0; nt < 4; nt++)
      aout[(size_t)(b * L + gq + r) * D + h * 64 + nt * 16 + li] = f2bf(O[nt][r] * inv);
  }
}

// ---------------- launcher ---------------------------------------------------
extern "C" void kernel_launch(void* const* d_in, const int* in_sizes, int n_in,
                              void* d_out, int out_size, void* d_ws, size_t ws_size,
                              hipStream_t stream) {
  const float* x      = (const float*)d_in[0];
  const float* w_qkv  = (const float*)d_in[1];
  const float* b_qkv  = (const float*)d_in[2];
  const float* w_proj = (const float*)d_in[3];
  const float* b_proj = (const float*)d_in[4];
  float* out = (float*)d_out;

  char* ws = (char*)d_ws;
  u16* x_bf     = (u16*)(ws);                         //  8 MB: [4096,1024] bf16
  u16* wqkv_bf  = (u16*)(ws + ((size_t)8  << 20));    //  6 MB: [3072,1024] bf16
  u16* wproj_bf = (u16*)(ws + ((size_t)14 << 20));    //  2 MB: [1024,1024] bf16
  u16* qkv_bf   = (u16*)(ws + ((size_t)16 << 20));    // 24 MB: [4096,3072] bf16
  u16* attn_bf  = (u16*)(ws + ((size_t)40 << 20));    //  8 MB: [4096,1024] bf16

  cast_all<<<2048, 256, 0, stream>>>(x, x_bf, w_qkv, wqkv_bf, w_proj, wproj_bf);

  // GEMM1: champion + LDS anti-conflict swizzle
  gemm_nt<1, 128, 128><<<(4096 / 128) * (3072 / 128), 256, 0, stream>>>(
      x_bf, wqkv_bf, b_qkv, qkv_bf, 4096, 3072, 1024);

  // attn: champion (frozen)
  attn_kernel<<<1024, 256, 0, stream>>>(qkv_bf, attn_bf);

  // GEMM2: 512-thread variant (2 waves/SIMD)
  gemm_nt64<<<(4096 / 128) * (1024 / 128), 512, 0, stream>>>(
      attn_bf, wproj_bf, b_proj, out, 4096, 1024, 1024);
}